// Round 2
// baseline (1628.684 us; speedup 1.0000x reference)
//
#include <hip/hip_runtime.h>
#include <stdint.h>

#define NH_ 32
#define HD_ 64
#define MBS_ 16
#define NMB_ 128
#define L_ 2048
#define W_ 2048
#define EPS_ 1e-6f

typedef unsigned short u16;
typedef unsigned int u32;
typedef __bf16 bf16x8 __attribute__((ext_vector_type(8)));
typedef float f32x4 __attribute__((ext_vector_type(4)));
typedef void __attribute__((address_space(1))) gvoid;
typedef void __attribute__((address_space(3))) lvoid;

__device__ __forceinline__ u16 to_bf16(float f) {
  union { float f; u32 u; } v; v.f = f;
  u32 r = v.u + 0x7fffu + ((v.u >> 16) & 1u);
  return (u16)(r >> 16);
}
__device__ __forceinline__ float bf2f(u16 u) {
  union { u32 u; float f; } v; v.u = ((u32)u) << 16; return v.f;
}

__device__ __forceinline__ float wredsum(float x) {
#pragma unroll
  for (int m = 1; m < 64; m <<= 1) x += __shfl_xor(x, m);
  return x;
}

// ---------------- fp32 -> bf16 convert (vectorized) ----------------
__global__ __launch_bounds__(256) void k_cvt(const float* __restrict__ in,
                                             u16* __restrict__ out, int n4) {
  int i = blockIdx.x * blockDim.x + threadIdx.x;
  if (i >= n4) return;
  float4 v = ((const float4*)in)[i];
  ushort4 o;
  o.x = to_bf16(v.x); o.y = to_bf16(v.y); o.z = to_bf16(v.z); o.w = to_bf16(v.w);
  ((ushort4*)out)[i] = o;
}

// ---------------- bf16 MFMA GEMM, C = A(MxK) * Bt(NxK)^T ----------------
// MODE 0: C fp32 row-major MxN.
// MODE 1: C bf16 scatter into scan layout [B][NH][NMB][16][64].
// MODE 2: C bf16 row-major MxN.
template <int MODE>
__global__ __launch_bounds__(256) void k_gemm(const u16* __restrict__ A,
                                              const u16* __restrict__ Bt,
                                              void* __restrict__ Cv,
                                              int M, int N, int K) {
  __shared__ u16 As[128 * 32];
  __shared__ u16 Bs[128 * 32];
  const int tid = threadIdx.x;
  const int wave = tid >> 6;
  const int lane = tid & 63;
  const int bn = blockIdx.x, bm = blockIdx.y;
  const int wr = wave >> 1, wc = wave & 1;

  f32x4 zero4 = {0.f, 0.f, 0.f, 0.f};
  f32x4 acc[4][4];
#pragma unroll
  for (int m = 0; m < 4; ++m)
#pragma unroll
    for (int n = 0; n < 4; ++n) acc[m][n] = zero4;

  const int e0 = wave * 512 + lane * 8;   // element offset in 128x32 tile
  const int r0 = e0 >> 5, c0 = e0 & 31;
  const u16* Ab = A + (size_t)(bm * 128) * K;
  const u16* Bb = Bt + (size_t)(bn * 128) * K;

  for (int k0 = 0; k0 < K; k0 += 32) {
    __builtin_amdgcn_global_load_lds((gvoid*)(Ab + (size_t)r0 * K + k0 + c0),
                                     (lvoid*)((char*)As + wave * 1024), 16, 0, 0);
    __builtin_amdgcn_global_load_lds((gvoid*)(Ab + (size_t)(r0 + 64) * K + k0 + c0),
                                     (lvoid*)((char*)As + 4096 + wave * 1024), 16, 0, 0);
    __builtin_amdgcn_global_load_lds((gvoid*)(Bb + (size_t)r0 * K + k0 + c0),
                                     (lvoid*)((char*)Bs + wave * 1024), 16, 0, 0);
    __builtin_amdgcn_global_load_lds((gvoid*)(Bb + (size_t)(r0 + 64) * K + k0 + c0),
                                     (lvoid*)((char*)Bs + 4096 + wave * 1024), 16, 0, 0);
    __syncthreads();
    const int fr = lane & 15;
    const int fk = (lane >> 4) * 8;
    bf16x8 af[4], bfv[4];
#pragma unroll
    for (int m = 0; m < 4; ++m)
      af[m] = *(const bf16x8*)&As[(wr * 64 + m * 16 + fr) * 32 + fk];
#pragma unroll
    for (int n = 0; n < 4; ++n)
      bfv[n] = *(const bf16x8*)&Bs[(wc * 64 + n * 16 + fr) * 32 + fk];
#pragma unroll
    for (int m = 0; m < 4; ++m)
#pragma unroll
      for (int n = 0; n < 4; ++n)
        acc[m][n] = __builtin_amdgcn_mfma_f32_16x16x32_bf16(af[m], bfv[n], acc[m][n], 0, 0, 0);
    __syncthreads();
  }

  const int fr = lane & 15;
  const int fq = lane >> 4;
#pragma unroll
  for (int m = 0; m < 4; ++m) {
#pragma unroll
    for (int n = 0; n < 4; ++n) {
      const int col = bn * 128 + wc * 64 + n * 16 + fr;
#pragma unroll
      for (int j = 0; j < 4; ++j) {
        const int row = bm * 128 + wr * 64 + m * 16 + fq * 4 + j;
        if (MODE == 0) {
          ((float*)Cv)[(size_t)row * N + col] = acc[m][n][j];
        } else if (MODE == 2) {
          ((u16*)Cv)[(size_t)row * N + col] = to_bf16(acc[m][n][j]);
        } else {
          const int b = row >> 11, l = row & 2047;
          const int h = col >> 6, d = col & 63;
          ((u16*)Cv)[((((size_t)b * NH_ + h) * NMB_ + (l >> 4)) * MBS_ + (l & 15)) * HD_ + d] =
              to_bf16(acc[m][n][j]);
        }
      }
    }
  }
}

// ---------------- ttt_lr sigmoid kernel (exact fp32) ----------------
// slr[b][h][n][j] = sigmoid(dot(hs[b, n*16+j, :], lr_w[h]) + lr_b[h]) / HD
__global__ __launch_bounds__(256) void k_slr(const float* __restrict__ hs,
                                             const float* __restrict__ lr_w,
                                             const float* __restrict__ lr_b,
                                             float* __restrict__ slr) {
  __shared__ float row[2048];
  __shared__ float part[32][9];
  const int r = blockIdx.x;            // b*2048 + l
  const int b = r >> 11, l = r & 2047;
  const int t = threadIdx.x;
  const float* src = hs + (size_t)r * 2048;
  ((float4*)row)[t] = ((const float4*)src)[t];
  ((float4*)row)[t + 256] = ((const float4*)src)[t + 256];
  __syncthreads();
  const int h = t >> 3, sub = t & 7;
  const float* w = lr_w + (size_t)h * 2048;
  float acc = 0.f;
#pragma unroll 4
  for (int e = 0; e < 64; ++e) {
    int idx = sub * 4 + 32 * e;
    float4 wv = *(const float4*)(w + idx);
    float4 rv = *(const float4*)(row + idx);
    acc += wv.x * rv.x + wv.y * rv.y + wv.z * rv.z + wv.w * rv.w;
  }
  part[h][sub] = acc;
  __syncthreads();
  if (t < 32) {
    float s = 0.f;
#pragma unroll
    for (int i = 0; i < 8; ++i) s += part[t][i];
    s += lr_b[t];
    float sg = 1.f / (1.f + expf(-s));
    slr[(((size_t)b * NH_ + t) * NMB_ + (l >> 4)) * MBS_ + (l & 15)] = sg * (1.0f / HD_);
  }
}

// ---------------- fused causal dwconv (q,k from xq) + RoPE + relayout ----------------
// xq is bf16 row-major [B][L][W]; outputs bf16 scan layout.
__global__ __launch_bounds__(256) void k_convrope(const u16* __restrict__ xq,
                                                  const float* __restrict__ cqw,
                                                  const float* __restrict__ cqb,
                                                  const float* __restrict__ ckw,
                                                  const float* __restrict__ ckb,
                                                  u16* __restrict__ XQs,
                                                  u16* __restrict__ XKs) {
  __shared__ float cosv[32], sinv[32];
  const int r = blockIdx.x;            // b*2048 + l
  const int b = r >> 11, l = r & 2047;
  const int t = threadIdx.x;
  if (t < 32) {
    float pos = (float)(l & 15);
    float inv_freq = expf(-(float)t * 0.28782313662425575f); // ln(10000)/32
    float ang = pos * inv_freq;
    cosv[t] = cosf(ang);
    sinv[t] = sinf(ang);
  }
  __syncthreads();
  const int c0 = t * 8;
  const int h = c0 >> 6, d0 = c0 & 63;
  float x[4][8];
#pragma unroll
  for (int dl = 0; dl < 4; ++dl) {
    int lrow = l - 3 + dl;
    if (lrow >= 0) {
      const u16* p = xq + ((size_t)b * L_ + lrow) * W_ + c0;
      ushort4 a = *(const ushort4*)p;
      ushort4 bb = *(const ushort4*)(p + 4);
      x[dl][0] = bf2f(a.x); x[dl][1] = bf2f(a.y); x[dl][2] = bf2f(a.z); x[dl][3] = bf2f(a.w);
      x[dl][4] = bf2f(bb.x); x[dl][5] = bf2f(bb.y); x[dl][6] = bf2f(bb.z); x[dl][7] = bf2f(bb.w);
    } else {
#pragma unroll
      for (int j = 0; j < 8; ++j) x[dl][j] = 0.f;
    }
  }
  float q8[8], k8[8];
#pragma unroll
  for (int j = 0; j < 8; ++j) {
    const int c = c0 + j;
    float aq = cqb[c], ak = ckb[c];
#pragma unroll
    for (int dl = 0; dl < 4; ++dl) {
      aq += x[dl][j] * cqw[c * 4 + dl];
      ak += x[dl][j] * ckw[c * 4 + dl];
    }
    q8[j] = aq; k8[j] = ak;
  }
  float oq[8], ok[8];
#pragma unroll
  for (int p = 0; p < 4; ++p) {
    const int kidx = (d0 >> 1) + p;
    const float cs = cosv[kidx], sn = sinv[kidx];
    float u = q8[2 * p], v = q8[2 * p + 1];
    oq[2 * p] = u * cs - v * sn;
    oq[2 * p + 1] = v * cs + u * sn;
    u = k8[2 * p]; v = k8[2 * p + 1];
    ok[2 * p] = u * cs - v * sn;
    ok[2 * p + 1] = v * cs + u * sn;
  }
  const size_t base =
      ((((size_t)b * NH_ + h) * NMB_ + (l >> 4)) * MBS_ + (l & 15)) * HD_ + d0;
  ushort4 oa, ob;
  oa.x = to_bf16(oq[0]); oa.y = to_bf16(oq[1]); oa.z = to_bf16(oq[2]); oa.w = to_bf16(oq[3]);
  ob.x = to_bf16(oq[4]); ob.y = to_bf16(oq[5]); ob.z = to_bf16(oq[6]); ob.w = to_bf16(oq[7]);
  *(ushort4*)(XQs + base) = oa;
  *(ushort4*)(XQs + base + 4) = ob;
  oa.x = to_bf16(ok[0]); oa.y = to_bf16(ok[1]); oa.z = to_bf16(ok[2]); oa.w = to_bf16(ok[3]);
  ob.x = to_bf16(ok[4]); ob.y = to_bf16(ok[5]); ob.z = to_bf16(ok[6]); ob.w = to_bf16(ok[7]);
  *(ushort4*)(XKs + base) = oa;
  *(ushort4*)(XKs + base + 4) = ob;
}

// ---------------- the TTT scan: one block per (b,h), fp32 math ----------------
__global__ __launch_bounds__(256) void k_scan(const u16* __restrict__ XQs,
                                              const u16* __restrict__ XKs,
                                              const u16* __restrict__ XVs,
                                              const float* __restrict__ slr,
                                              const float* __restrict__ lti,
                                              const float* __restrict__ nw,
                                              const float* __restrict__ nb,
                                              const float* __restrict__ W1in,
                                              const float* __restrict__ b1in,
                                              u16* __restrict__ outp) {
  __shared__ float sxq[16][68], sxk[16][68], sxv[16][68];
  __shared__ float sxqT[64][20], sxkT[64][20];
  __shared__ float sgrad[16][68];
  __shared__ float part[2][4][16][64];
  __shared__ float sA[16][16];
  __shared__ float ss[16];

  const int t = threadIdx.x;
  const int c = t & 63;     // column lane (HD dim)
  const int q = t >> 6;     // wave id = d-quarter / row-group
  const int bh = blockIdx.x;
  const int h = bh & (NH_ - 1);

  const float gamma = nw[h * HD_ + c];
  const float beta = nb[h * HD_ + c];

  float tokr[4];
#pragma unroll
  for (int jj = 0; jj < 4; ++jj) {
    int i = q * 4 + jj;
    float ti = 1.f / (float)(i + 1) + lti[i];
    tokr[jj] = ti > 0.f ? ti : 0.f;
  }
  float t15 = 1.f / 16.f + lti[15];
  const float tok15 = t15 > 0.f ? t15 : 0.f;

  float W1r[16];  // W1[q*16+dd][c]
#pragma unroll
  for (int dd = 0; dd < 16; ++dd)
    W1r[dd] = W1in[((size_t)h * HD_ + q * 16 + dd) * HD_ + c];
  float b1c = b1in[h * HD_ + c];

  const size_t tb0 = (size_t)bh * (NMB_ * MBS_ * HD_);
  const int rr = t >> 4;
  const int dblk = (t & 15) * 4;

  for (int n = 0; n < NMB_; ++n) {
    const size_t tb = tb0 + (size_t)n * (MBS_ * HD_);
    // ---- load tiles (bf16 -> fp32) ----
    {
      ushort4 uq = *(const ushort4*)(XQs + tb + t * 4);
      ushort4 uk = *(const ushort4*)(XKs + tb + t * 4);
      ushort4 uv = *(const ushort4*)(XVs + tb + t * 4);
      float4 vq = {bf2f(uq.x), bf2f(uq.y), bf2f(uq.z), bf2f(uq.w)};
      float4 vk = {bf2f(uk.x), bf2f(uk.y), bf2f(uk.z), bf2f(uk.w)};
      float4 vv = {bf2f(uv.x), bf2f(uv.y), bf2f(uv.z), bf2f(uv.w)};
      *(float4*)&sxq[rr][dblk] = vq;
      *(float4*)&sxk[rr][dblk] = vk;
      *(float4*)&sxv[rr][dblk] = vv;
      sxqT[dblk + 0][rr] = vq.x; sxqT[dblk + 1][rr] = vq.y;
      sxqT[dblk + 2][rr] = vq.z; sxqT[dblk + 3][rr] = vq.w;
      sxkT[dblk + 0][rr] = vk.x; sxkT[dblk + 1][rr] = vk.y;
      sxkT[dblk + 2][rr] = vk.z; sxkT[dblk + 3][rr] = vk.w;
      if (t < 16) ss[t] = slr[(size_t)bh * (NMB_ * MBS_) + n * MBS_ + t];
    }
    __syncthreads();

    // ---- Phase B: d-partitioned partials of xk@W1 and xq@W1 (old W1) ----
    float pZ[16], pQ[16];
#pragma unroll
    for (int r2 = 0; r2 < 16; ++r2) { pZ[r2] = 0.f; pQ[r2] = 0.f; }
#pragma unroll
    for (int dd = 0; dd < 16; ++dd) {
      const int d = q * 16 + dd;
      const float w1v = W1r[dd];
#pragma unroll
      for (int g4 = 0; g4 < 4; ++g4) {
        float4 kv = *(const float4*)&sxkT[d][g4 * 4];
        float4 qv = *(const float4*)&sxqT[d][g4 * 4];
        pZ[g4 * 4 + 0] += kv.x * w1v; pZ[g4 * 4 + 1] += kv.y * w1v;
        pZ[g4 * 4 + 2] += kv.z * w1v; pZ[g4 * 4 + 3] += kv.w * w1v;
        pQ[g4 * 4 + 0] += qv.x * w1v; pQ[g4 * 4 + 1] += qv.y * w1v;
        pQ[g4 * 4 + 2] += qv.z * w1v; pQ[g4 * 4 + 3] += qv.w * w1v;
      }
    }
#pragma unroll
    for (int r2 = 0; r2 < 16; ++r2) {
      part[0][q][r2][c] = pZ[r2];
      part[1][q][r2][c] = pQ[r2];
    }
    // ---- Phase D: Attn1 = tril(xq @ xk^T), write sA[i][j] = s[j]*(Attn+1) ----
    {
      const int ai = t >> 4, aj = t & 15;
      float a = 0.f;
#pragma unroll
      for (int g4 = 0; g4 < 16; ++g4) {
        float4 qv = *(const float4*)&sxq[ai][g4 * 4];
        float4 kv = *(const float4*)&sxk[aj][g4 * 4];
        a += qv.x * kv.x + qv.y * kv.y + qv.z * kv.z + qv.w * kv.w;
      }
      sA[ai][aj] = (aj <= ai) ? ss[aj] * (a + 1.f) : 0.f;
    }
    __syncthreads();

    // ---- Phase C: reduce Z1, ln_l2_bwd -> grad ----
    float zq_pre[4];
#pragma unroll
    for (int jj = 0; jj < 4; ++jj) {
      const int r2 = q * 4 + jj;
      float z = part[0][0][r2][c] + part[0][1][r2][c] + part[0][2][r2][c] +
                part[0][3][r2][c] + b1c;
      zq_pre[jj] = part[1][0][r2][c] + part[1][1][r2][c] + part[1][2][r2][c] +
                   part[1][3][r2][c] + b1c;
      const float target = sxv[r2][c] - sxk[r2][c];
      float mu = wredsum(z) * (1.f / 64.f);
      float dz = z - mu;
      float var = wredsum(dz * dz) * (1.f / 64.f);
      float stdv = sqrtf(var + EPS_);
      float xh = dz / stdv;
      float gy = (gamma * xh + beta - target) * gamma;
      float sgy = wredsum(gy);
      float sgyxh = wredsum(gy * xh);
      sgrad[r2][c] = (64.f * gy - sgy - xh * sgyxh) / (64.f * stdv);
    }
    __syncthreads();

    // ---- Phase E: Z1_bar, ln_fwd, output ----
    float g16[16];
#pragma unroll
    for (int j = 0; j < 16; ++j) g16[j] = sgrad[j][c];
#pragma unroll
    for (int jj = 0; jj < 4; ++jj) {
      const int r2 = q * 4 + jj;
      float t1 = 0.f;
#pragma unroll
      for (int g4 = 0; g4 < 4; ++g4) {
        float4 av = *(const float4*)&sA[r2][g4 * 4];
        t1 += av.x * g16[g4 * 4 + 0] + av.y * g16[g4 * 4 + 1] +
              av.z * g16[g4 * 4 + 2] + av.w * g16[g4 * 4 + 3];
      }
      float zb = zq_pre[jj] - tokr[jj] * t1;
      float mu = wredsum(zb) * (1.f / 64.f);
      float dz = zb - mu;
      float var = wredsum(dz * dz) * (1.f / 64.f);
      float xh = dz * rsqrtf(var + EPS_);
      outp[tb + r2 * HD_ + c] = to_bf16(sxq[r2][c] + gamma * xh + beta);
    }
    // ---- Phase F: state update (W1 regs, b1 reg) ----
    float bsum = 0.f;
    float gl[16];
#pragma unroll
    for (int j = 0; j < 16; ++j) {
      float sg = ss[j] * g16[j];
      bsum += sg;
      gl[j] = tok15 * sg;
    }
    b1c -= tok15 * bsum;
#pragma unroll
    for (int dd = 0; dd < 16; ++dd) {
      const int d = q * 16 + dd;
      float acc2 = 0.f;
#pragma unroll
      for (int g4 = 0; g4 < 4; ++g4) {
        float4 kv = *(const float4*)&sxkT[d][g4 * 4];
        acc2 += kv.x * gl[g4 * 4 + 0] + kv.y * gl[g4 * 4 + 1] +
                kv.z * gl[g4 * 4 + 2] + kv.w * gl[g4 * 4 + 3];
      }
      W1r[dd] -= acc2;
    }
    __syncthreads();
  }
}

// ---------------- post-LN + bf16 pack (gather from scan layout) ----------------
__global__ __launch_bounds__(256) void k_postln(const u16* __restrict__ so,
                                                const float* __restrict__ pnw,
                                                const float* __restrict__ pnb,
                                                u16* __restrict__ out_bf) {
  __shared__ float red[2][4];
  const int r = blockIdx.x;            // b*2048 + l
  const int b = r >> 11, l = r & 2047;
  const int t = threadIdx.x;
  const int h = t >> 3, d0 = (t & 7) * 8;
  const size_t base =
      ((((size_t)b * NH_ + h) * NMB_ + (l >> 4)) * MBS_ + (l & 15)) * HD_ + d0;
  ushort4 ua = *(const ushort4*)(so + base);
  ushort4 ub = *(const ushort4*)(so + base + 4);
  float v[8];
  v[0] = bf2f(ua.x); v[1] = bf2f(ua.y); v[2] = bf2f(ua.z); v[3] = bf2f(ua.w);
  v[4] = bf2f(ub.x); v[5] = bf2f(ub.y); v[6] = bf2f(ub.z); v[7] = bf2f(ub.w);
  float s = 0.f, sq = 0.f;
#pragma unroll
  for (int j = 0; j < 8; ++j) { s += v[j]; sq += v[j] * v[j]; }
  s = wredsum(s);
  sq = wredsum(sq);
  const int wave = t >> 6, lane = t & 63;
  if (lane == 0) { red[0][wave] = s; red[1][wave] = sq; }
  __syncthreads();
  s = red[0][0] + red[0][1] + red[0][2] + red[0][3];
  sq = red[1][0] + red[1][1] + red[1][2] + red[1][3];
  float mu = s * (1.f / 2048.f);
  float var = sq * (1.f / 2048.f) - mu * mu;
  float rstd = rsqrtf(var + EPS_);
  const int c = h * 64 + d0;
  ushort4 o1, o2;
  float nv;
  nv = (v[0] - mu) * rstd * pnw[c + 0] + pnb[c + 0]; o1.x = to_bf16(nv);
  nv = (v[1] - mu) * rstd * pnw[c + 1] + pnb[c + 1]; o1.y = to_bf16(nv);
  nv = (v[2] - mu) * rstd * pnw[c + 2] + pnb[c + 2]; o1.z = to_bf16(nv);
  nv = (v[3] - mu) * rstd * pnw[c + 3] + pnb[c + 3]; o1.w = to_bf16(nv);
  nv = (v[4] - mu) * rstd * pnw[c + 4] + pnb[c + 4]; o2.x = to_bf16(nv);
  nv = (v[5] - mu) * rstd * pnw[c + 5] + pnb[c + 5]; o2.y = to_bf16(nv);
  nv = (v[6] - mu) * rstd * pnw[c + 6] + pnb[c + 6]; o2.z = to_bf16(nv);
  nv = (v[7] - mu) * rstd * pnw[c + 7] + pnb[c + 7]; o2.w = to_bf16(nv);
  u16* dst = out_bf + (size_t)r * 2048 + c;
  *(ushort4*)dst = o1;
  *(ushort4*)(dst + 4) = o2;
}

extern "C" void kernel_launch(void* const* d_in, const int* in_sizes, int n_in,
                              void* d_out, int out_size, void* d_ws, size_t ws_size,
                              hipStream_t stream) {
  const float* hs = (const float*)d_in[0];
  const float* q_w = (const float*)d_in[1];
  const float* v_w = (const float*)d_in[2];
  const float* o_w = (const float*)d_in[3];
  const float* cqw = (const float*)d_in[4];
  const float* cqb = (const float*)d_in[5];
  const float* ckw = (const float*)d_in[6];
  const float* ckb = (const float*)d_in[7];
  const float* lrw = (const float*)d_in[8];
  const float* lrb = (const float*)d_in[9];
  const float* lti = (const float*)d_in[10];
  const float* tnw = (const float*)d_in[11];
  const float* tnb = (const float*)d_in[12];
  const float* W1in = (const float*)d_in[13];
  const float* b1in = (const float*)d_in[14];
  const float* pnw = (const float*)d_in[15];
  const float* pnb = (const float*)d_in[16];

  // Workspace layout (145 MiB total, regions time-aliased):
  // P0 [0,32M):    hs_bf          -> XQ_bf (conv writes after v-GEMM done)
  // P1 [32M,64M):  xq_bf          -> scan_out (bf16)
  // P2 [64M,96M):  XK_bf          -> normed (bf16, post-LN out)
  // P3 [96M,128M): XV_bf
  // P4 [128M,136M): qw_bf         -> ow_bf (converted after q-GEMM done)
  // P5 [136M,144M): vw_bf
  // P6 [144M,145M): slr (fp32)
  char* ws = (char*)d_ws;
  u16* hs_bf  = (u16*)(ws + 0);
  u16* XQs    = (u16*)(ws + 0);
  u16* xq_bf  = (u16*)(ws + 33554432);
  u16* scano  = (u16*)(ws + 33554432);
  u16* XKs    = (u16*)(ws + 67108864);
  u16* normed = (u16*)(ws + 67108864);
  u16* XVs    = (u16*)(ws + 100663296);
  u16* qw_bf  = (u16*)(ws + 134217728);
  u16* ow_bf  = (u16*)(ws + 134217728);
  u16* vw_bf  = (u16*)(ws + 142606336);
  float* slr  = (float*)(ws + 150994944);   // end: 152,043,520 bytes
  float* outp = (float*)d_out;

  // 1) convert inputs to bf16
  k_cvt<<<16384, 256, 0, stream>>>(hs, hs_bf, 4194304);
  k_cvt<<<4096, 256, 0, stream>>>(q_w, qw_bf, 1048576);
  k_cvt<<<4096, 256, 0, stream>>>(v_w, vw_bf, 1048576);

  // 2) projections
  dim3 gg(16, 64);  // N/128, M/128
  k_gemm<2><<<gg, 256, 0, stream>>>(hs_bf, qw_bf, xq_bf, 8192, 2048, 2048);
  k_gemm<1><<<gg, 256, 0, stream>>>(hs_bf, vw_bf, XVs, 8192, 2048, 2048);

  // ow conversion (reuses qw region; q-GEMM is already ordered before this)
  k_cvt<<<4096, 256, 0, stream>>>(o_w, ow_bf, 1048576);

  // 3) sigmoid lr (exact fp32, reads original hs)
  k_slr<<<8192, 256, 0, stream>>>(hs, lrw, lrb, slr);

  // 4) conv + rope + relayout (writes XQ into former hs_bf region)
  k_convrope<<<8192, 256, 0, stream>>>(xq_bf, cqw, cqb, ckw, ckb, XQs, XKs);

  // 5) sequential TTT scan (scan_out overwrites xq region)
  k_scan<<<128, 256, 0, stream>>>(XQs, XKs, XVs, slr, lti, tnw, tnb, W1in, b1in,
                                  scano);

  // 6) post-LN + pack bf16 (normed overwrites XK region)
  k_postln<<<8192, 256, 0, stream>>>(scano, pnw, pnb, normed);

  // 7) output projection (fp32 out)
  k_gemm<0><<<gg, 256, 0, stream>>>(normed, ow_bf, outp, 8192, 2048, 2048);
}

// Round 3
// 1523.676 us; speedup vs baseline: 1.0689x; 1.0689x over previous
//
#include <hip/hip_runtime.h>
#include <stdint.h>

#define NH_ 32
#define HD_ 64
#define MBS_ 16
#define NMB_ 128
#define L_ 2048
#define W_ 2048
#define EPS_ 1e-6f

typedef unsigned short u16;
typedef unsigned int u32;
typedef __bf16 bf16x8 __attribute__((ext_vector_type(8)));
typedef float f32x4 __attribute__((ext_vector_type(4)));
typedef void __attribute__((address_space(1))) gvoid;
typedef void __attribute__((address_space(3))) lvoid;

__device__ __forceinline__ u16 to_bf16(float f) {
  union { float f; u32 u; } v; v.f = f;
  u32 r = v.u + 0x7fffu + ((v.u >> 16) & 1u);
  return (u16)(r >> 16);
}
__device__ __forceinline__ float bf2f(u16 u) {
  union { u32 u; float f; } v; v.u = ((u32)u) << 16; return v.f;
}

__device__ __forceinline__ float wredsum(float x) {
#pragma unroll
  for (int m = 1; m < 64; m <<= 1) x += __shfl_xor(x, m);
  return x;
}

// ---------------- fp32 -> bf16 convert (vectorized) ----------------
__global__ __launch_bounds__(256) void k_cvt(const float* __restrict__ in,
                                             u16* __restrict__ out, int n4) {
  int i = blockIdx.x * blockDim.x + threadIdx.x;
  if (i >= n4) return;
  float4 v = ((const float4*)in)[i];
  ushort4 o;
  o.x = to_bf16(v.x); o.y = to_bf16(v.y); o.z = to_bf16(v.z); o.w = to_bf16(v.w);
  ((ushort4*)out)[i] = o;
}

// ---------------- bf16 MFMA GEMM, C = A(MxK) * Bt(NxK)^T ----------------
// MODE 0: C fp32 row-major MxN.
// MODE 1: C bf16 scatter into scan layout [B][NH][NMB][16][64].
// MODE 2: C bf16 row-major MxN.
template <int MODE>
__global__ __launch_bounds__(256) void k_gemm(const u16* __restrict__ A,
                                              const u16* __restrict__ Bt,
                                              void* __restrict__ Cv,
                                              int M, int N, int K) {
  __shared__ u16 As[128 * 32];
  __shared__ u16 Bs[128 * 32];
  const int tid = threadIdx.x;
  const int wave = tid >> 6;
  const int lane = tid & 63;
  const int bn = blockIdx.x, bm = blockIdx.y;
  const int wr = wave >> 1, wc = wave & 1;

  f32x4 zero4 = {0.f, 0.f, 0.f, 0.f};
  f32x4 acc[4][4];
#pragma unroll
  for (int m = 0; m < 4; ++m)
#pragma unroll
    for (int n = 0; n < 4; ++n) acc[m][n] = zero4;

  const int e0 = wave * 512 + lane * 8;   // element offset in 128x32 tile
  const int r0 = e0 >> 5, c0 = e0 & 31;
  const u16* Ab = A + (size_t)(bm * 128) * K;
  const u16* Bb = Bt + (size_t)(bn * 128) * K;

  for (int k0 = 0; k0 < K; k0 += 32) {
    __builtin_amdgcn_global_load_lds((gvoid*)(Ab + (size_t)r0 * K + k0 + c0),
                                     (lvoid*)((char*)As + wave * 1024), 16, 0, 0);
    __builtin_amdgcn_global_load_lds((gvoid*)(Ab + (size_t)(r0 + 64) * K + k0 + c0),
                                     (lvoid*)((char*)As + 4096 + wave * 1024), 16, 0, 0);
    __builtin_amdgcn_global_load_lds((gvoid*)(Bb + (size_t)r0 * K + k0 + c0),
                                     (lvoid*)((char*)Bs + wave * 1024), 16, 0, 0);
    __builtin_amdgcn_global_load_lds((gvoid*)(Bb + (size_t)(r0 + 64) * K + k0 + c0),
                                     (lvoid*)((char*)Bs + 4096 + wave * 1024), 16, 0, 0);
    __syncthreads();
    const int fr = lane & 15;
    const int fk = (lane >> 4) * 8;
    bf16x8 af[4], bfv[4];
#pragma unroll
    for (int m = 0; m < 4; ++m)
      af[m] = *(const bf16x8*)&As[(wr * 64 + m * 16 + fr) * 32 + fk];
#pragma unroll
    for (int n = 0; n < 4; ++n)
      bfv[n] = *(const bf16x8*)&Bs[(wc * 64 + n * 16 + fr) * 32 + fk];
#pragma unroll
    for (int m = 0; m < 4; ++m)
#pragma unroll
      for (int n = 0; n < 4; ++n)
        acc[m][n] = __builtin_amdgcn_mfma_f32_16x16x32_bf16(af[m], bfv[n], acc[m][n], 0, 0, 0);
    __syncthreads();
  }

  const int fr = lane & 15;
  const int fq = lane >> 4;
#pragma unroll
  for (int m = 0; m < 4; ++m) {
#pragma unroll
    for (int n = 0; n < 4; ++n) {
      const int col = bn * 128 + wc * 64 + n * 16 + fr;
#pragma unroll
      for (int j = 0; j < 4; ++j) {
        const int row = bm * 128 + wr * 64 + m * 16 + fq * 4 + j;
        if (MODE == 0) {
          ((float*)Cv)[(size_t)row * N + col] = acc[m][n][j];
        } else if (MODE == 2) {
          ((u16*)Cv)[(size_t)row * N + col] = to_bf16(acc[m][n][j]);
        } else {
          const int b = row >> 11, l = row & 2047;
          const int h = col >> 6, d = col & 63;
          ((u16*)Cv)[((((size_t)b * NH_ + h) * NMB_ + (l >> 4)) * MBS_ + (l & 15)) * HD_ + d] =
              to_bf16(acc[m][n][j]);
        }
      }
    }
  }
}

// ---------------- ttt_lr sigmoid kernel (exact fp32) ----------------
__global__ __launch_bounds__(256) void k_slr(const float* __restrict__ hs,
                                             const float* __restrict__ lr_w,
                                             const float* __restrict__ lr_b,
                                             float* __restrict__ slr) {
  __shared__ float row[2048];
  __shared__ float part[32][9];
  const int r = blockIdx.x;            // b*2048 + l
  const int b = r >> 11, l = r & 2047;
  const int t = threadIdx.x;
  const float* src = hs + (size_t)r * 2048;
  ((float4*)row)[t] = ((const float4*)src)[t];
  ((float4*)row)[t + 256] = ((const float4*)src)[t + 256];
  __syncthreads();
  const int h = t >> 3, sub = t & 7;
  const float* w = lr_w + (size_t)h * 2048;
  float acc = 0.f;
#pragma unroll 4
  for (int e = 0; e < 64; ++e) {
    int idx = sub * 4 + 32 * e;
    float4 wv = *(const float4*)(w + idx);
    float4 rv = *(const float4*)(row + idx);
    acc += wv.x * rv.x + wv.y * rv.y + wv.z * rv.z + wv.w * rv.w;
  }
  part[h][sub] = acc;
  __syncthreads();
  if (t < 32) {
    float s = 0.f;
#pragma unroll
    for (int i = 0; i < 8; ++i) s += part[t][i];
    s += lr_b[t];
    float sg = 1.f / (1.f + expf(-s));
    slr[(((size_t)b * NH_ + t) * NMB_ + (l >> 4)) * MBS_ + (l & 15)] = sg * (1.0f / HD_);
  }
}

// ---------------- fused causal dwconv (q,k from xq) + RoPE + relayout ----------------
__global__ __launch_bounds__(256) void k_convrope(const u16* __restrict__ xq,
                                                  const float* __restrict__ cqw,
                                                  const float* __restrict__ cqb,
                                                  const float* __restrict__ ckw,
                                                  const float* __restrict__ ckb,
                                                  u16* __restrict__ XQs,
                                                  u16* __restrict__ XKs) {
  __shared__ float cosv[32], sinv[32];
  const int r = blockIdx.x;            // b*2048 + l
  const int b = r >> 11, l = r & 2047;
  const int t = threadIdx.x;
  if (t < 32) {
    float pos = (float)(l & 15);
    float inv_freq = expf(-(float)t * 0.28782313662425575f); // ln(10000)/32
    float ang = pos * inv_freq;
    cosv[t] = cosf(ang);
    sinv[t] = sinf(ang);
  }
  __syncthreads();
  const int c0 = t * 8;
  const int h = c0 >> 6, d0 = c0 & 63;
  float x[4][8];
#pragma unroll
  for (int dl = 0; dl < 4; ++dl) {
    int lrow = l - 3 + dl;
    if (lrow >= 0) {
      const u16* p = xq + ((size_t)b * L_ + lrow) * W_ + c0;
      ushort4 a = *(const ushort4*)p;
      ushort4 bb = *(const ushort4*)(p + 4);
      x[dl][0] = bf2f(a.x); x[dl][1] = bf2f(a.y); x[dl][2] = bf2f(a.z); x[dl][3] = bf2f(a.w);
      x[dl][4] = bf2f(bb.x); x[dl][5] = bf2f(bb.y); x[dl][6] = bf2f(bb.z); x[dl][7] = bf2f(bb.w);
    } else {
#pragma unroll
      for (int j = 0; j < 8; ++j) x[dl][j] = 0.f;
    }
  }
  float q8[8], k8[8];
#pragma unroll
  for (int j = 0; j < 8; ++j) {
    const int c = c0 + j;
    float aq = cqb[c], ak = ckb[c];
#pragma unroll
    for (int dl = 0; dl < 4; ++dl) {
      aq += x[dl][j] * cqw[c * 4 + dl];
      ak += x[dl][j] * ckw[c * 4 + dl];
    }
    q8[j] = aq; k8[j] = ak;
  }
  float oq[8], ok[8];
#pragma unroll
  for (int p = 0; p < 4; ++p) {
    const int kidx = (d0 >> 1) + p;
    const float cs = cosv[kidx], sn = sinv[kidx];
    float u = q8[2 * p], v = q8[2 * p + 1];
    oq[2 * p] = u * cs - v * sn;
    oq[2 * p + 1] = v * cs + u * sn;
    u = k8[2 * p]; v = k8[2 * p + 1];
    ok[2 * p] = u * cs - v * sn;
    ok[2 * p + 1] = v * cs + u * sn;
  }
  const size_t base =
      ((((size_t)b * NH_ + h) * NMB_ + (l >> 4)) * MBS_ + (l & 15)) * HD_ + d0;
  ushort4 oa, ob;
  oa.x = to_bf16(oq[0]); oa.y = to_bf16(oq[1]); oa.z = to_bf16(oq[2]); oa.w = to_bf16(oq[3]);
  ob.x = to_bf16(oq[4]); ob.y = to_bf16(oq[5]); ob.z = to_bf16(oq[6]); ob.w = to_bf16(oq[7]);
  *(ushort4*)(XQs + base) = oa;
  *(ushort4*)(XQs + base + 4) = ob;
  oa.x = to_bf16(ok[0]); oa.y = to_bf16(ok[1]); oa.z = to_bf16(ok[2]); oa.w = to_bf16(ok[3]);
  ob.x = to_bf16(ok[4]); ob.y = to_bf16(ok[5]); ob.z = to_bf16(ok[6]); ob.w = to_bf16(ok[7]);
  *(ushort4*)(XKs + base) = oa;
  *(ushort4*)(XKs + base + 4) = ob;
}

// ---------------- the TTT scan: one block of 512 threads per (b,h) ----------------
// 8 waves: waves 0-3 compute Z-partials (d-quarter q), waves 4-7 Q-partials.
// W1 quarter (q&3) is register-replicated in wave pairs (q, q+4) and updated
// identically (bitwise same op order -> stays in sync).
// sxqT/sxkT transposes use a 4-float-block XOR swizzle to cut write conflicts
// from 8-way to ~4-way while keeping b128-aligned broadcast reads.
__global__ __launch_bounds__(512) void k_scan(const u16* __restrict__ XQs,
                                              const u16* __restrict__ XKs,
                                              const u16* __restrict__ XVs,
                                              const float* __restrict__ slr,
                                              const float* __restrict__ lti,
                                              const float* __restrict__ nw,
                                              const float* __restrict__ nb,
                                              const float* __restrict__ W1in,
                                              const float* __restrict__ b1in,
                                              u16* __restrict__ outp) {
  __shared__ float sxq[16][68], sxk[16][68], sxv[16][68];
  __shared__ float sxqT[64 * 20], sxkT[64 * 20];
  __shared__ float sgrad[16][68];
  __shared__ float part[2][4][16][64];
  __shared__ float sA[16][16];
  __shared__ float ss[16];

  const int t = threadIdx.x;
  const int c = t & 63;     // column lane (HD dim)
  const int q = t >> 6;     // wave id 0..7
  const int qq = q & 3;     // W1 d-quarter owned by this wave
  const int bh = blockIdx.x;
  const int h = bh & (NH_ - 1);

  const float gamma = nw[h * HD_ + c];
  const float beta = nb[h * HD_ + c];

  float tok2[2];
#pragma unroll
  for (int jj = 0; jj < 2; ++jj) {
    int i = q * 2 + jj;
    float ti = 1.f / (float)(i + 1) + lti[i];
    tok2[jj] = ti > 0.f ? ti : 0.f;
  }
  float t15 = 1.f / 16.f + lti[15];
  const float tok15 = t15 > 0.f ? t15 : 0.f;

  float W1r[16];  // W1[qq*16+dd][c]
#pragma unroll
  for (int dd = 0; dd < 16; ++dd)
    W1r[dd] = W1in[((size_t)h * HD_ + qq * 16 + dd) * HD_ + c];
  float b1c = b1in[h * HD_ + c];

  const size_t tb0 = (size_t)bh * (NMB_ * MBS_ * HD_);
  // store-phase ids (t<256 only)
  const int rr = t >> 4;           // 0..15
  const int dblk = (t & 15) * 4;
  const int relem = rr & 3;
  const int swzw = ((rr >> 2) ^ (t & 3)) << 2;  // write-side block swizzle

  ushort4 puq, puk, puv;
  if (t < 256) {
    puq = *(const ushort4*)(XQs + tb0 + t * 4);
    puk = *(const ushort4*)(XKs + tb0 + t * 4);
    puv = *(const ushort4*)(XVs + tb0 + t * 4);
  }

  for (int n = 0; n < NMB_; ++n) {
    const size_t tb = tb0 + (size_t)n * (MBS_ * HD_);
    // ---- store current tile (from prefetch regs), then prefetch next ----
    if (t < 256) {
      float4 vq = {bf2f(puq.x), bf2f(puq.y), bf2f(puq.z), bf2f(puq.w)};
      float4 vk = {bf2f(puk.x), bf2f(puk.y), bf2f(puk.z), bf2f(puk.w)};
      float4 vv = {bf2f(puv.x), bf2f(puv.y), bf2f(puv.z), bf2f(puv.w)};
      *(float4*)&sxq[rr][dblk] = vq;
      *(float4*)&sxk[rr][dblk] = vk;
      *(float4*)&sxv[rr][dblk] = vv;
      const int tba = dblk * 20 + swzw + relem;   // addr for i: + i*20
      sxqT[tba + 0]  = vq.x; sxqT[tba + 20] = vq.y;
      sxqT[tba + 40] = vq.z; sxqT[tba + 60] = vq.w;
      sxkT[tba + 0]  = vk.x; sxkT[tba + 20] = vk.y;
      sxkT[tba + 40] = vk.z; sxkT[tba + 60] = vk.w;
    }
    if (t < 16) ss[t] = slr[(size_t)bh * (NMB_ * MBS_) + n * MBS_ + t];
    if (t < 256) {
      const size_t tbn = tb0 + (size_t)((n + 1 < NMB_) ? n + 1 : n) * (MBS_ * HD_);
      puq = *(const ushort4*)(XQs + tbn + t * 4);
      puk = *(const ushort4*)(XKs + tbn + t * 4);
      puv = *(const ushort4*)(XVs + tbn + t * 4);
    }
    __syncthreads();

    // ---- Phase B: Z partials (waves 0-3) / Q partials (waves 4-7) ----
    if (q < 4) {
      float pZ[16];
#pragma unroll
      for (int r2 = 0; r2 < 16; ++r2) pZ[r2] = 0.f;
#pragma unroll
      for (int dd = 0; dd < 16; ++dd) {
        const float w1v = W1r[dd];
        const int dbase = (qq * 16 + dd) * 20;
        const int sw2 = (dd >> 2) & 3;
#pragma unroll
        for (int g4 = 0; g4 < 4; ++g4) {
          float4 kv = *(const float4*)&sxkT[dbase + ((g4 ^ sw2) << 2)];
          pZ[g4 * 4 + 0] += kv.x * w1v; pZ[g4 * 4 + 1] += kv.y * w1v;
          pZ[g4 * 4 + 2] += kv.z * w1v; pZ[g4 * 4 + 3] += kv.w * w1v;
        }
      }
#pragma unroll
      for (int r2 = 0; r2 < 16; ++r2) part[0][qq][r2][c] = pZ[r2];
      // ---- Phase D: Attn (low half only): sA[i][j] = s[j]*(tril(xq xk^T)+1)
      {
        const int ai = t >> 4, aj = t & 15;
        float a = 0.f;
#pragma unroll
        for (int g4 = 0; g4 < 16; ++g4) {
          float4 qv = *(const float4*)&sxq[ai][g4 * 4];
          float4 kv = *(const float4*)&sxk[aj][g4 * 4];
          a += qv.x * kv.x + qv.y * kv.y + qv.z * kv.z + qv.w * kv.w;
        }
        sA[ai][aj] = (aj <= ai) ? ss[aj] * (a + 1.f) : 0.f;
      }
    } else {
      float pQ[16];
#pragma unroll
      for (int r2 = 0; r2 < 16; ++r2) pQ[r2] = 0.f;
#pragma unroll
      for (int dd = 0; dd < 16; ++dd) {
        const float w1v = W1r[dd];
        const int dbase = (qq * 16 + dd) * 20;
        const int sw2 = (dd >> 2) & 3;
#pragma unroll
        for (int g4 = 0; g4 < 4; ++g4) {
          float4 qv = *(const float4*)&sxqT[dbase + ((g4 ^ sw2) << 2)];
          pQ[g4 * 4 + 0] += qv.x * w1v; pQ[g4 * 4 + 1] += qv.y * w1v;
          pQ[g4 * 4 + 2] += qv.z * w1v; pQ[g4 * 4 + 3] += qv.w * w1v;
        }
      }
#pragma unroll
      for (int r2 = 0; r2 < 16; ++r2) part[1][qq][r2][c] = pQ[r2];
    }
    __syncthreads();

    // ---- Phase C: rows 2q, 2q+1: reduce Z1, ln_l2_bwd -> grad ----
    float zq_pre[2];
#pragma unroll
    for (int jj = 0; jj < 2; ++jj) {
      const int r2 = q * 2 + jj;
      float z = part[0][0][r2][c] + part[0][1][r2][c] + part[0][2][r2][c] +
                part[0][3][r2][c] + b1c;
      zq_pre[jj] = part[1][0][r2][c] + part[1][1][r2][c] + part[1][2][r2][c] +
                   part[1][3][r2][c] + b1c;
      const float target = sxv[r2][c] - sxk[r2][c];
      float mu = wredsum(z) * (1.f / 64.f);
      float dz = z - mu;
      float var = wredsum(dz * dz) * (1.f / 64.f);
      float stdv = sqrtf(var + EPS_);
      float xh = dz / stdv;
      float gy = (gamma * xh + beta - target) * gamma;
      float sgy = wredsum(gy);
      float sgyxh = wredsum(gy * xh);
      sgrad[r2][c] = (64.f * gy - sgy - xh * sgyxh) / (64.f * stdv);
    }
    __syncthreads();

    // ---- Phase E: rows 2q, 2q+1: Z1_bar, ln_fwd, output ----
    float g16[16];
#pragma unroll
    for (int j = 0; j < 16; ++j) g16[j] = sgrad[j][c];
#pragma unroll
    for (int jj = 0; jj < 2; ++jj) {
      const int r2 = q * 2 + jj;
      float t1 = 0.f;
#pragma unroll
      for (int g4 = 0; g4 < 4; ++g4) {
        float4 av = *(const float4*)&sA[r2][g4 * 4];
        t1 += av.x * g16[g4 * 4 + 0] + av.y * g16[g4 * 4 + 1] +
              av.z * g16[g4 * 4 + 2] + av.w * g16[g4 * 4 + 3];
      }
      float zb = zq_pre[jj] - tok2[jj] * t1;
      float mu = wredsum(zb) * (1.f / 64.f);
      float dz = zb - mu;
      float var = wredsum(dz * dz) * (1.f / 64.f);
      float xh = dz * rsqrtf(var + EPS_);
      outp[tb + r2 * HD_ + c] = to_bf16(sxq[r2][c] + gamma * xh + beta);
    }
    // ---- Phase F: state update (all 8 waves; wave pairs stay in sync) ----
    float bsum = 0.f;
    float gl[16];
#pragma unroll
    for (int j = 0; j < 16; ++j) {
      float sg = ss[j] * g16[j];
      bsum += sg;
      gl[j] = tok15 * sg;
    }
    b1c -= tok15 * bsum;
#pragma unroll
    for (int dd = 0; dd < 16; ++dd) {
      const int dbase = (qq * 16 + dd) * 20;
      const int sw2 = (dd >> 2) & 3;
      float acc2 = 0.f;
#pragma unroll
      for (int g4 = 0; g4 < 4; ++g4) {
        float4 kv = *(const float4*)&sxkT[dbase + ((g4 ^ sw2) << 2)];
        acc2 += kv.x * gl[g4 * 4 + 0] + kv.y * gl[g4 * 4 + 1] +
                kv.z * gl[g4 * 4 + 2] + kv.w * gl[g4 * 4 + 3];
      }
      W1r[dd] -= acc2;
    }
    __syncthreads();
  }
}

// ---------------- post-LN + bf16 pack (gather from scan layout) ----------------
__global__ __launch_bounds__(256) void k_postln(const u16* __restrict__ so,
                                                const float* __restrict__ pnw,
                                                const float* __restrict__ pnb,
                                                u16* __restrict__ out_bf) {
  __shared__ float red[2][4];
  const int r = blockIdx.x;            // b*2048 + l
  const int b = r >> 11, l = r & 2047;
  const int t = threadIdx.x;
  const int h = t >> 3, d0 = (t & 7) * 8;
  const size_t base =
      ((((size_t)b * NH_ + h) * NMB_ + (l >> 4)) * MBS_ + (l & 15)) * HD_ + d0;
  ushort4 ua = *(const ushort4*)(so + base);
  ushort4 ub = *(const ushort4*)(so + base + 4);
  float v[8];
  v[0] = bf2f(ua.x); v[1] = bf2f(ua.y); v[2] = bf2f(ua.z); v[3] = bf2f(ua.w);
  v[4] = bf2f(ub.x); v[5] = bf2f(ub.y); v[6] = bf2f(ub.z); v[7] = bf2f(ub.w);
  float s = 0.f, sq = 0.f;
#pragma unroll
  for (int j = 0; j < 8; ++j) { s += v[j]; sq += v[j] * v[j]; }
  s = wredsum(s);
  sq = wredsum(sq);
  const int wave = t >> 6, lane = t & 63;
  if (lane == 0) { red[0][wave] = s; red[1][wave] = sq; }
  __syncthreads();
  s = red[0][0] + red[0][1] + red[0][2] + red[0][3];
  sq = red[1][0] + red[1][1] + red[1][2] + red[1][3];
  float mu = s * (1.f / 2048.f);
  float var = sq * (1.f / 2048.f) - mu * mu;
  float rstd = rsqrtf(var + EPS_);
  const int c = h * 64 + d0;
  ushort4 o1, o2;
  float nv;
  nv = (v[0] - mu) * rstd * pnw[c + 0] + pnb[c + 0]; o1.x = to_bf16(nv);
  nv = (v[1] - mu) * rstd * pnw[c + 1] + pnb[c + 1]; o1.y = to_bf16(nv);
  nv = (v[2] - mu) * rstd * pnw[c + 2] + pnb[c + 2]; o1.z = to_bf16(nv);
  nv = (v[3] - mu) * rstd * pnw[c + 3] + pnb[c + 3]; o1.w = to_bf16(nv);
  nv = (v[4] - mu) * rstd * pnw[c + 4] + pnb[c + 4]; o2.x = to_bf16(nv);
  nv = (v[5] - mu) * rstd * pnw[c + 5] + pnb[c + 5]; o2.y = to_bf16(nv);
  nv = (v[6] - mu) * rstd * pnw[c + 6] + pnb[c + 6]; o2.z = to_bf16(nv);
  nv = (v[7] - mu) * rstd * pnw[c + 7] + pnb[c + 7]; o2.w = to_bf16(nv);
  u16* dst = out_bf + (size_t)r * 2048 + c;
  *(ushort4*)dst = o1;
  *(ushort4*)(dst + 4) = o2;
}

extern "C" void kernel_launch(void* const* d_in, const int* in_sizes, int n_in,
                              void* d_out, int out_size, void* d_ws, size_t ws_size,
                              hipStream_t stream) {
  const float* hs = (const float*)d_in[0];
  const float* q_w = (const float*)d_in[1];
  const float* v_w = (const float*)d_in[2];
  const float* o_w = (const float*)d_in[3];
  const float* cqw = (const float*)d_in[4];
  const float* cqb = (const float*)d_in[5];
  const float* ckw = (const float*)d_in[6];
  const float* ckb = (const float*)d_in[7];
  const float* lrw = (const float*)d_in[8];
  const float* lrb = (const float*)d_in[9];
  const float* lti = (const float*)d_in[10];
  const float* tnw = (const float*)d_in[11];
  const float* tnb = (const float*)d_in[12];
  const float* W1in = (const float*)d_in[13];
  const float* b1in = (const float*)d_in[14];
  const float* pnw = (const float*)d_in[15];
  const float* pnb = (const float*)d_in[16];

  // Workspace layout (145 MiB total, regions time-aliased):
  // P0 [0,32M):    hs_bf          -> XQ_bf (conv writes after v-GEMM done)
  // P1 [32M,64M):  xq_bf          -> scan_out (bf16)
  // P2 [64M,96M):  XK_bf          -> normed (bf16, post-LN out)
  // P3 [96M,128M): XV_bf
  // P4 [128M,136M): qw_bf         -> ow_bf (converted after q-GEMM done)
  // P5 [136M,144M): vw_bf
  // P6 [144M,145M): slr (fp32)
  char* ws = (char*)d_ws;
  u16* hs_bf  = (u16*)(ws + 0);
  u16* XQs    = (u16*)(ws + 0);
  u16* xq_bf  = (u16*)(ws + 33554432);
  u16* scano  = (u16*)(ws + 33554432);
  u16* XKs    = (u16*)(ws + 67108864);
  u16* normed = (u16*)(ws + 67108864);
  u16* XVs    = (u16*)(ws + 100663296);
  u16* qw_bf  = (u16*)(ws + 134217728);
  u16* ow_bf  = (u16*)(ws + 134217728);
  u16* vw_bf  = (u16*)(ws + 142606336);
  float* slr  = (float*)(ws + 150994944);   // end: 152,043,520 bytes
  float* outp = (float*)d_out;

  // 1) convert inputs to bf16
  k_cvt<<<16384, 256, 0, stream>>>(hs, hs_bf, 4194304);
  k_cvt<<<4096, 256, 0, stream>>>(q_w, qw_bf, 1048576);
  k_cvt<<<4096, 256, 0, stream>>>(v_w, vw_bf, 1048576);

  // 2) projections
  dim3 gg(16, 64);  // N/128, M/128
  k_gemm<2><<<gg, 256, 0, stream>>>(hs_bf, qw_bf, xq_bf, 8192, 2048, 2048);
  k_gemm<1><<<gg, 256, 0, stream>>>(hs_bf, vw_bf, XVs, 8192, 2048, 2048);

  // ow conversion (reuses qw region; q-GEMM is already ordered before this)
  k_cvt<<<4096, 256, 0, stream>>>(o_w, ow_bf, 1048576);

  // 3) sigmoid lr (exact fp32, reads original hs)
  k_slr<<<8192, 256, 0, stream>>>(hs, lrw, lrb, slr);

  // 4) conv + rope + relayout (writes XQ into former hs_bf region)
  k_convrope<<<8192, 256, 0, stream>>>(xq_bf, cqw, cqb, ckw, ckb, XQs, XKs);

  // 5) sequential TTT scan (scan_out overwrites xq region)
  k_scan<<<128, 512, 0, stream>>>(XQs, XKs, XVs, slr, lti, tnw, tnb, W1in, b1in,
                                  scano);

  // 6) post-LN + pack bf16 (normed overwrites XK region)
  k_postln<<<8192, 256, 0, stream>>>(scano, pnw, pnb, normed);

  // 7) output projection (fp32 out)
  k_gemm<0><<<gg, 256, 0, stream>>>(normed, ow_bf, outp, 8192, 2048, 2048);
}

// Round 4
// 944.999 us; speedup vs baseline: 1.7235x; 1.6124x over previous
//
#include <hip/hip_runtime.h>
#include <stdint.h>

#define NH_ 32
#define HD_ 64
#define MBS_ 16
#define NMB_ 128
#define L_ 2048
#define W_ 2048
#define EPS_ 1e-6f

typedef unsigned short u16;
typedef unsigned int u32;
typedef __bf16 bf16x8 __attribute__((ext_vector_type(8)));
typedef float f32x4 __attribute__((ext_vector_type(4)));
typedef void __attribute__((address_space(1))) gvoid;
typedef void __attribute__((address_space(3))) lvoid;

union BF8 { u16 u[8]; bf16x8 v; };

__device__ __forceinline__ u16 to_bf16(float f) {
  union { float f; u32 u; } v; v.f = f;
  u32 r = v.u + 0x7fffu + ((v.u >> 16) & 1u);
  return (u16)(r >> 16);
}
__device__ __forceinline__ float bf2f(u16 u) {
  union { u32 u; float f; } v; v.u = ((u32)u) << 16; return v.f;
}
__device__ __forceinline__ void pack_hl(float f, u16& hi, u16& lo) {
  hi = to_bf16(f);
  lo = to_bf16(f - bf2f(hi));
}

__device__ __forceinline__ float wredsum(float x) {
#pragma unroll
  for (int m = 1; m < 64; m <<= 1) x += __shfl_xor(x, m);
  return x;
}

// ---------------- fp32 -> bf16 convert (vectorized) ----------------
__global__ __launch_bounds__(256) void k_cvt(const float* __restrict__ in,
                                             u16* __restrict__ out, int n4) {
  int i = blockIdx.x * blockDim.x + threadIdx.x;
  if (i >= n4) return;
  float4 v = ((const float4*)in)[i];
  ushort4 o;
  o.x = to_bf16(v.x); o.y = to_bf16(v.y); o.z = to_bf16(v.z); o.w = to_bf16(v.w);
  ((ushort4*)out)[i] = o;
}

// ---------------- bf16 MFMA GEMM, C = A(MxK) * Bt(NxK)^T ----------------
template <int MODE>
__global__ __launch_bounds__(256) void k_gemm(const u16* __restrict__ A,
                                              const u16* __restrict__ Bt,
                                              void* __restrict__ Cv,
                                              int M, int N, int K) {
  __shared__ u16 As[128 * 32];
  __shared__ u16 Bs[128 * 32];
  const int tid = threadIdx.x;
  const int wave = tid >> 6;
  const int lane = tid & 63;
  const int bn = blockIdx.x, bm = blockIdx.y;
  const int wr = wave >> 1, wc = wave & 1;

  f32x4 zero4 = {0.f, 0.f, 0.f, 0.f};
  f32x4 acc[4][4];
#pragma unroll
  for (int m = 0; m < 4; ++m)
#pragma unroll
    for (int n = 0; n < 4; ++n) acc[m][n] = zero4;

  const int e0 = wave * 512 + lane * 8;
  const int r0 = e0 >> 5, c0 = e0 & 31;
  const u16* Ab = A + (size_t)(bm * 128) * K;
  const u16* Bb = Bt + (size_t)(bn * 128) * K;

  for (int k0 = 0; k0 < K; k0 += 32) {
    __builtin_amdgcn_global_load_lds((gvoid*)(Ab + (size_t)r0 * K + k0 + c0),
                                     (lvoid*)((char*)As + wave * 1024), 16, 0, 0);
    __builtin_amdgcn_global_load_lds((gvoid*)(Ab + (size_t)(r0 + 64) * K + k0 + c0),
                                     (lvoid*)((char*)As + 4096 + wave * 1024), 16, 0, 0);
    __builtin_amdgcn_global_load_lds((gvoid*)(Bb + (size_t)r0 * K + k0 + c0),
                                     (lvoid*)((char*)Bs + wave * 1024), 16, 0, 0);
    __builtin_amdgcn_global_load_lds((gvoid*)(Bb + (size_t)(r0 + 64) * K + k0 + c0),
                                     (lvoid*)((char*)Bs + 4096 + wave * 1024), 16, 0, 0);
    __syncthreads();
    const int fr = lane & 15;
    const int fk = (lane >> 4) * 8;
    bf16x8 af[4], bfv[4];
#pragma unroll
    for (int m = 0; m < 4; ++m)
      af[m] = *(const bf16x8*)&As[(wr * 64 + m * 16 + fr) * 32 + fk];
#pragma unroll
    for (int n = 0; n < 4; ++n)
      bfv[n] = *(const bf16x8*)&Bs[(wc * 64 + n * 16 + fr) * 32 + fk];
#pragma unroll
    for (int m = 0; m < 4; ++m)
#pragma unroll
      for (int n = 0; n < 4; ++n)
        acc[m][n] = __builtin_amdgcn_mfma_f32_16x16x32_bf16(af[m], bfv[n], acc[m][n], 0, 0, 0);
    __syncthreads();
  }

  const int fr = lane & 15;
  const int fq = lane >> 4;
#pragma unroll
  for (int m = 0; m < 4; ++m) {
#pragma unroll
    for (int n = 0; n < 4; ++n) {
      const int col = bn * 128 + wc * 64 + n * 16 + fr;
#pragma unroll
      for (int j = 0; j < 4; ++j) {
        const int row = bm * 128 + wr * 64 + m * 16 + fq * 4 + j;
        if (MODE == 0) {
          ((float*)Cv)[(size_t)row * N + col] = acc[m][n][j];
        } else if (MODE == 2) {
          ((u16*)Cv)[(size_t)row * N + col] = to_bf16(acc[m][n][j]);
        } else {
          const int b = row >> 11, l = row & 2047;
          const int h = col >> 6, d = col & 63;
          ((u16*)Cv)[((((size_t)b * NH_ + h) * NMB_ + (l >> 4)) * MBS_ + (l & 15)) * HD_ + d] =
              to_bf16(acc[m][n][j]);
        }
      }
    }
  }
}

// ---------------- ttt_lr sigmoid kernel (exact fp32) ----------------
__global__ __launch_bounds__(256) void k_slr(const float* __restrict__ hs,
                                             const float* __restrict__ lr_w,
                                             const float* __restrict__ lr_b,
                                             float* __restrict__ slr) {
  __shared__ float row[2048];
  __shared__ float part[32][9];
  const int r = blockIdx.x;
  const int b = r >> 11, l = r & 2047;
  const int t = threadIdx.x;
  const float* src = hs + (size_t)r * 2048;
  ((float4*)row)[t] = ((const float4*)src)[t];
  ((float4*)row)[t + 256] = ((const float4*)src)[t + 256];
  __syncthreads();
  const int h = t >> 3, sub = t & 7;
  const float* w = lr_w + (size_t)h * 2048;
  float acc = 0.f;
#pragma unroll 4
  for (int e = 0; e < 64; ++e) {
    int idx = sub * 4 + 32 * e;
    float4 wv = *(const float4*)(w + idx);
    float4 rv = *(const float4*)(row + idx);
    acc += wv.x * rv.x + wv.y * rv.y + wv.z * rv.z + wv.w * rv.w;
  }
  part[h][sub] = acc;
  __syncthreads();
  if (t < 32) {
    float s = 0.f;
#pragma unroll
    for (int i = 0; i < 8; ++i) s += part[t][i];
    s += lr_b[t];
    float sg = 1.f / (1.f + expf(-s));
    slr[(((size_t)b * NH_ + t) * NMB_ + (l >> 4)) * MBS_ + (l & 15)] = sg * (1.0f / HD_);
  }
}

// ---------------- fused causal dwconv (q,k from xq) + RoPE + relayout ----------------
__global__ __launch_bounds__(256) void k_convrope(const u16* __restrict__ xq,
                                                  const float* __restrict__ cqw,
                                                  const float* __restrict__ cqb,
                                                  const float* __restrict__ ckw,
                                                  const float* __restrict__ ckb,
                                                  u16* __restrict__ XQs,
                                                  u16* __restrict__ XKs) {
  __shared__ float cosv[32], sinv[32];
  const int r = blockIdx.x;
  const int b = r >> 11, l = r & 2047;
  const int t = threadIdx.x;
  if (t < 32) {
    float pos = (float)(l & 15);
    float inv_freq = expf(-(float)t * 0.28782313662425575f);
    float ang = pos * inv_freq;
    cosv[t] = cosf(ang);
    sinv[t] = sinf(ang);
  }
  __syncthreads();
  const int c0 = t * 8;
  const int h = c0 >> 6, d0 = c0 & 63;
  float x[4][8];
#pragma unroll
  for (int dl = 0; dl < 4; ++dl) {
    int lrow = l - 3 + dl;
    if (lrow >= 0) {
      const u16* p = xq + ((size_t)b * L_ + lrow) * W_ + c0;
      ushort4 a = *(const ushort4*)p;
      ushort4 bb = *(const ushort4*)(p + 4);
      x[dl][0] = bf2f(a.x); x[dl][1] = bf2f(a.y); x[dl][2] = bf2f(a.z); x[dl][3] = bf2f(a.w);
      x[dl][4] = bf2f(bb.x); x[dl][5] = bf2f(bb.y); x[dl][6] = bf2f(bb.z); x[dl][7] = bf2f(bb.w);
    } else {
#pragma unroll
      for (int j = 0; j < 8; ++j) x[dl][j] = 0.f;
    }
  }
  float q8[8], k8[8];
#pragma unroll
  for (int j = 0; j < 8; ++j) {
    const int c = c0 + j;
    float aq = cqb[c], ak = ckb[c];
#pragma unroll
    for (int dl = 0; dl < 4; ++dl) {
      aq += x[dl][j] * cqw[c * 4 + dl];
      ak += x[dl][j] * ckw[c * 4 + dl];
    }
    q8[j] = aq; k8[j] = ak;
  }
  float oq[8], ok[8];
#pragma unroll
  for (int p = 0; p < 4; ++p) {
    const int kidx = (d0 >> 1) + p;
    const float cs = cosv[kidx], sn = sinv[kidx];
    float u = q8[2 * p], v = q8[2 * p + 1];
    oq[2 * p] = u * cs - v * sn;
    oq[2 * p + 1] = v * cs + u * sn;
    u = k8[2 * p]; v = k8[2 * p + 1];
    ok[2 * p] = u * cs - v * sn;
    ok[2 * p + 1] = v * cs + u * sn;
  }
  const size_t base =
      ((((size_t)b * NH_ + h) * NMB_ + (l >> 4)) * MBS_ + (l & 15)) * HD_ + d0;
  ushort4 oa, ob;
  oa.x = to_bf16(oq[0]); oa.y = to_bf16(oq[1]); oa.z = to_bf16(oq[2]); oa.w = to_bf16(oq[3]);
  ob.x = to_bf16(oq[4]); ob.y = to_bf16(oq[5]); ob.z = to_bf16(oq[6]); ob.w = to_bf16(oq[7]);
  *(ushort4*)(XQs + base) = oa;
  *(ushort4*)(XQs + base + 4) = ob;
  oa.x = to_bf16(ok[0]); oa.y = to_bf16(ok[1]); oa.z = to_bf16(ok[2]); oa.w = to_bf16(ok[3]);
  ob.x = to_bf16(ok[4]); ob.y = to_bf16(ok[5]); ob.z = to_bf16(ok[6]); ob.w = to_bf16(ok[7]);
  *(ushort4*)(XKs + base) = oa;
  *(ushort4*)(XKs + base + 4) = ob;
}

// ---------------- the TTT scan: MFMA-based, 256 threads (4 waves) per (b,h) ----------------
// Wave w owns output col-block [16w,16w+16). W1 master fp32 in registers (D-layout),
// staged to LDS each step as bf16 hi+lo fragments. LN reductions over 16 lanes only.
#define MFMA16(A, B, C) __builtin_amdgcn_mfma_f32_16x16x32_bf16((A), (B), (C), 0, 0, 0)

__global__ __launch_bounds__(256) void k_scan(const u16* __restrict__ XQs,
                                              const u16* __restrict__ XKs,
                                              const u16* __restrict__ XVs,
                                              const float* __restrict__ slr,
                                              const float* __restrict__ lti,
                                              const float* __restrict__ nw,
                                              const float* __restrict__ nb,
                                              const float* __restrict__ W1in,
                                              const float* __restrict__ b1in,
                                              u16* __restrict__ outp) {
  __shared__ u16 sxq[2][16][72], sxk[2][16][72], sxv[2][16][72];
  __shared__ u16 sket[2][64][24];     // (eta15*XK)^T bf16, [d][r]
  __shared__ float ssl[2][16];
  __shared__ u16 w1h[64][72], w1l[64][72];  // W1^T [n][d] bf16 hi/lo
  __shared__ float z1l[16][68];
  __shared__ float zbl[16][68];
  __shared__ u16 gh[16][72], glo[16][72];   // grad bf16 hi/lo row-major
  __shared__ u16 sal[16][24];               // sA bf16 [i][j]
  __shared__ float nwl[64], nbl[64];

  const int t = threadIdx.x;
  const int lane = t & 63;
  const int w = t >> 6;       // wave / col-block
  const int c = lane & 15;
  const int s = lane >> 4;    // 0..3
  const int bh = blockIdx.x;
  const int h = bh & (NH_ - 1);

  // token coefficients for row index i = 4s+reg
  float tokr[4];
#pragma unroll
  for (int reg = 0; reg < 4; ++reg) {
    int i = 4 * s + reg;
    float ti = 1.f / (float)(i + 1) + lti[i];
    tokr[reg] = ti > 0.f ? ti : 0.f;
  }
  float t15 = 1.f / 16.f + lti[15];
  const float tok15 = t15 > 0.f ? t15 : 0.f;

  // W1 master: W1r[mt*4+reg] = W1[16mt+4s+reg][16w+c]
  float W1r[16];
  const float* w1p = W1in + (size_t)h * 4096;
#pragma unroll
  for (int mt = 0; mt < 4; ++mt)
#pragma unroll
    for (int reg = 0; reg < 4; ++reg)
      W1r[mt * 4 + reg] = w1p[(16 * mt + 4 * s + reg) * 64 + 16 * w + c];
  float b1c = b1in[h * 64 + 16 * w + c];

  if (t < 64) { nwl[t] = nw[h * 64 + t]; nbl[t] = nb[h * 64 + t]; }

  // initial W1 staging
#pragma unroll
  for (int mt = 0; mt < 4; ++mt) {
    ushort4 hv, lv;
    pack_hl(W1r[mt * 4 + 0], hv.x, lv.x);
    pack_hl(W1r[mt * 4 + 1], hv.y, lv.y);
    pack_hl(W1r[mt * 4 + 2], hv.z, lv.z);
    pack_hl(W1r[mt * 4 + 3], hv.w, lv.w);
    *(ushort4*)&w1h[16 * w + c][16 * mt + 4 * s] = hv;
    *(ushort4*)&w1l[16 * w + c][16 * mt + 4 * s] = lv;
  }

  const size_t tb0 = (size_t)bh * (NMB_ * MBS_ * HD_);
  const int rr = t >> 4, dblk = (t & 15) * 4;

  // prefetch tile 0
  ushort4 pq = *(const ushort4*)(XQs + tb0 + t * 4);
  ushort4 pk = *(const ushort4*)(XKs + tb0 + t * 4);
  ushort4 pv = *(const ushort4*)(XVs + tb0 + t * 4);
  float ssA = slr[(size_t)bh * 2048 + rr];
  float ssB = (t < 16) ? slr[(size_t)bh * 2048 + t] : 0.f;

  f32x4 zero4 = {0.f, 0.f, 0.f, 0.f};

  for (int n = 0; n < NMB_; ++n) {
    const int p = n & 1;
    const size_t tb = tb0 + (size_t)n * (MBS_ * HD_);
    // ---- A: stage tiles + eta-scaled XK^T, prefetch next ----
    *(ushort4*)&sxq[p][rr][dblk] = pq;
    *(ushort4*)&sxk[p][rr][dblk] = pk;
    *(ushort4*)&sxv[p][rr][dblk] = pv;
    {
      float e15r = tok15 * ssA;
      sket[p][dblk + 0][rr] = to_bf16(bf2f(pk.x) * e15r);
      sket[p][dblk + 1][rr] = to_bf16(bf2f(pk.y) * e15r);
      sket[p][dblk + 2][rr] = to_bf16(bf2f(pk.z) * e15r);
      sket[p][dblk + 3][rr] = to_bf16(bf2f(pk.w) * e15r);
    }
    if (t < 16) ssl[p][t] = ssB;
    {
      const int nn = (n + 1 < NMB_) ? n + 1 : n;
      const size_t tbn = tb0 + (size_t)nn * (MBS_ * HD_);
      pq = *(const ushort4*)(XQs + tbn + t * 4);
      pk = *(const ushort4*)(XKs + tbn + t * 4);
      pv = *(const ushort4*)(XVs + tbn + t * 4);
      ssA = slr[(size_t)bh * 2048 + nn * 16 + rr];
      if (t < 16) ssB = slr[(size_t)bh * 2048 + nn * 16 + t];
    }
    __syncthreads();

    // ---- B: Z1, Z1q, Attn^T via MFMA ----
    bf16x8 xkf0 = *(const bf16x8*)&sxk[p][c][8 * s];
    bf16x8 xkf1 = *(const bf16x8*)&sxk[p][c][32 + 8 * s];
    bf16x8 xqf0 = *(const bf16x8*)&sxq[p][c][8 * s];
    bf16x8 xqf1 = *(const bf16x8*)&sxq[p][c][32 + 8 * s];
    bf16x8 wh0 = *(const bf16x8*)&w1h[16 * w + c][8 * s];
    bf16x8 wh1 = *(const bf16x8*)&w1h[16 * w + c][32 + 8 * s];
    bf16x8 wl0 = *(const bf16x8*)&w1l[16 * w + c][8 * s];
    bf16x8 wl1 = *(const bf16x8*)&w1l[16 * w + c][32 + 8 * s];
    f32x4 z1a = zero4;
    z1a = MFMA16(xkf0, wh0, z1a);
    z1a = MFMA16(xkf1, wh1, z1a);
    z1a = MFMA16(xkf0, wl0, z1a);
    z1a = MFMA16(xkf1, wl1, z1a);
    f32x4 zqa = zero4;
    zqa = MFMA16(xqf0, wh0, zqa);
    zqa = MFMA16(xqf1, wh1, zqa);
    zqa = MFMA16(xqf0, wl0, zqa);
    zqa = MFMA16(xqf1, wl1, zqa);
    f32x4 ata = zero4;
    ata = MFMA16(xkf0, xqf0, ata);   // D[j][i] = Attn[i=c][j=4s+reg]
    ata = MFMA16(xkf1, xqf1, ata);
    // e15 broadcast fragment (for b1 update MFMA)
    BF8 ef;
#pragma unroll
    for (int j = 0; j < 8; ++j)
      ef.u[j] = to_bf16(tok15 * ssl[p][(8 * s + j) & 15]);
    // sA = (j<=i) ? ss[j]*(Attn+1) : 0  (lane holds i=c, j=4s+reg)
    if (w == 0) {
      ushort4 sa4;
      {
        int j0 = 4 * s;
        float a0 = (j0 + 0 <= c) ? ssl[p][j0 + 0] * (ata[0] + 1.f) : 0.f;
        float a1 = (j0 + 1 <= c) ? ssl[p][j0 + 1] * (ata[1] + 1.f) : 0.f;
        float a2 = (j0 + 2 <= c) ? ssl[p][j0 + 2] * (ata[2] + 1.f) : 0.f;
        float a3 = (j0 + 3 <= c) ? ssl[p][j0 + 3] * (ata[3] + 1.f) : 0.f;
        sa4.x = to_bf16(a0); sa4.y = to_bf16(a1); sa4.z = to_bf16(a2); sa4.w = to_bf16(a3);
      }
      *(ushort4*)&sal[c][4 * s] = sa4;
    }
    // Z1 (+old b1) to LDS for LN
#pragma unroll
    for (int reg = 0; reg < 4; ++reg)
      z1l[4 * s + reg][16 * w + c] = z1a[reg] + b1c;
    __syncthreads();

    // ---- C: LN-L2-bwd -> grad (row r = 4w+s, lane handles d=4c..4c+3) ----
    const int r = 4 * w + s;
    {
      float4 z4 = *(const float4*)&z1l[r][4 * c];
      ushort4 kv4 = *(const ushort4*)&sxk[p][r][4 * c];
      ushort4 vv4 = *(const ushort4*)&sxv[p][r][4 * c];
      float tg0 = bf2f(vv4.x) - bf2f(kv4.x);
      float tg1 = bf2f(vv4.y) - bf2f(kv4.y);
      float tg2 = bf2f(vv4.z) - bf2f(kv4.z);
      float tg3 = bf2f(vv4.w) - bf2f(kv4.w);
      float s1 = z4.x + z4.y + z4.z + z4.w;
      float s2 = z4.x * z4.x + z4.y * z4.y + z4.z * z4.z + z4.w * z4.w;
#pragma unroll
      for (int m = 1; m < 16; m <<= 1) { s1 += __shfl_xor(s1, m); s2 += __shfl_xor(s2, m); }
      float mu = s1 * (1.f / 64.f);
      float var = s2 * (1.f / 64.f) - mu * mu;
      float rstd = rsqrtf(var + EPS_);
      float4 gv = *(const float4*)&nwl[4 * c];
      float4 bv = *(const float4*)&nbl[4 * c];
      float xh0 = (z4.x - mu) * rstd, xh1 = (z4.y - mu) * rstd;
      float xh2 = (z4.z - mu) * rstd, xh3 = (z4.w - mu) * rstd;
      float gy0 = (gv.x * xh0 + bv.x - tg0) * gv.x;
      float gy1 = (gv.y * xh1 + bv.y - tg1) * gv.y;
      float gy2 = (gv.z * xh2 + bv.z - tg2) * gv.z;
      float gy3 = (gv.w * xh3 + bv.w - tg3) * gv.w;
      float sg = gy0 + gy1 + gy2 + gy3;
      float sgx = gy0 * xh0 + gy1 * xh1 + gy2 * xh2 + gy3 * xh3;
#pragma unroll
      for (int m = 1; m < 16; m <<= 1) { sg += __shfl_xor(sg, m); sgx += __shfl_xor(sgx, m); }
      float sc = rstd * (1.f / 64.f);
      float g0 = (64.f * gy0 - sg - xh0 * sgx) * sc;
      float g1 = (64.f * gy1 - sg - xh1 * sgx) * sc;
      float g2 = (64.f * gy2 - sg - xh2 * sgx) * sc;
      float g3 = (64.f * gy3 - sg - xh3 * sgx) * sc;
      ushort4 hv, lv;
      pack_hl(g0, hv.x, lv.x); pack_hl(g1, hv.y, lv.y);
      pack_hl(g2, hv.z, lv.z); pack_hl(g3, hv.w, lv.w);
      *(ushort4*)&gh[r][4 * c] = hv;
      *(ushort4*)&glo[r][4 * c] = lv;
    }
    __syncthreads();

    // ---- D: C1 = sA@grad, dW1, b1 update, Z1bar ----
    {
      BF8 gf;
      const int rb = 8 * (s & 1);
      if (s < 2) {
#pragma unroll
        for (int j = 0; j < 8; ++j) gf.u[j] = gh[rb + j][16 * w + c];
      } else {
#pragma unroll
        for (int j = 0; j < 8; ++j) gf.u[j] = glo[rb + j][16 * w + c];
      }
      bf16x8 saf = *(const bf16x8*)&sal[c][8 * (s & 1)];
      bf16x8 ke0 = *(const bf16x8*)&sket[p][c][8 * (s & 1)];
      bf16x8 ke1 = *(const bf16x8*)&sket[p][16 + c][8 * (s & 1)];
      bf16x8 ke2 = *(const bf16x8*)&sket[p][32 + c][8 * (s & 1)];
      bf16x8 ke3 = *(const bf16x8*)&sket[p][48 + c][8 * (s & 1)];
      f32x4 c1a = MFMA16(saf, gf.v, zero4);
      f32x4 b1a = MFMA16(ef.v, gf.v, zero4);
      f32x4 dw0 = MFMA16(ke0, gf.v, zero4);
      f32x4 dw1 = MFMA16(ke1, gf.v, zero4);
      f32x4 dw2 = MFMA16(ke2, gf.v, zero4);
      f32x4 dw3 = MFMA16(ke3, gf.v, zero4);
      // Z1bar with OLD b1
#pragma unroll
      for (int reg = 0; reg < 4; ++reg)
        zbl[4 * s + reg][16 * w + c] = zqa[reg] + b1c - tokr[reg] * c1a[reg];
      // state update
      b1c -= b1a[0];
#pragma unroll
      for (int reg = 0; reg < 4; ++reg) {
        W1r[0 + reg] -= dw0[reg];
        W1r[4 + reg] -= dw1[reg];
        W1r[8 + reg] -= dw2[reg];
        W1r[12 + reg] -= dw3[reg];
      }
      // restage W1 hi/lo
#pragma unroll
      for (int mt = 0; mt < 4; ++mt) {
        ushort4 hv, lv;
        pack_hl(W1r[mt * 4 + 0], hv.x, lv.x);
        pack_hl(W1r[mt * 4 + 1], hv.y, lv.y);
        pack_hl(W1r[mt * 4 + 2], hv.z, lv.z);
        pack_hl(W1r[mt * 4 + 3], hv.w, lv.w);
        *(ushort4*)&w1h[16 * w + c][16 * mt + 4 * s] = hv;
        *(ushort4*)&w1l[16 * w + c][16 * mt + 4 * s] = lv;
      }
    }
    __syncthreads();

    // ---- E: ln_fwd(Z1bar) + XQ -> out ----
    {
      float4 zb4 = *(const float4*)&zbl[r][4 * c];
      float s1 = zb4.x + zb4.y + zb4.z + zb4.w;
      float s2 = zb4.x * zb4.x + zb4.y * zb4.y + zb4.z * zb4.z + zb4.w * zb4.w;
#pragma unroll
      for (int m = 1; m < 16; m <<= 1) { s1 += __shfl_xor(s1, m); s2 += __shfl_xor(s2, m); }
      float mu = s1 * (1.f / 64.f);
      float var = s2 * (1.f / 64.f) - mu * mu;
      float rstd = rsqrtf(var + EPS_);
      float4 gv = *(const float4*)&nwl[4 * c];
      float4 bv = *(const float4*)&nbl[4 * c];
      ushort4 q4 = *(const ushort4*)&sxq[p][r][4 * c];
      ushort4 o4;
      o4.x = to_bf16(bf2f(q4.x) + gv.x * ((zb4.x - mu) * rstd) + bv.x);
      o4.y = to_bf16(bf2f(q4.y) + gv.y * ((zb4.y - mu) * rstd) + bv.y);
      o4.z = to_bf16(bf2f(q4.z) + gv.z * ((zb4.z - mu) * rstd) + bv.z);
      o4.w = to_bf16(bf2f(q4.w) + gv.w * ((zb4.w - mu) * rstd) + bv.w);
      *(ushort4*)&outp[tb + r * HD_ + 4 * c] = o4;
    }
  }
}

// ---------------- post-LN + bf16 pack ----------------
__global__ __launch_bounds__(256) void k_postln(const u16* __restrict__ so,
                                                const float* __restrict__ pnw,
                                                const float* __restrict__ pnb,
                                                u16* __restrict__ out_bf) {
  __shared__ float red[2][4];
  const int r = blockIdx.x;
  const int b = r >> 11, l = r & 2047;
  const int t = threadIdx.x;
  const int h = t >> 3, d0 = (t & 7) * 8;
  const size_t base =
      ((((size_t)b * NH_ + h) * NMB_ + (l >> 4)) * MBS_ + (l & 15)) * HD_ + d0;
  ushort4 ua = *(const ushort4*)(so + base);
  ushort4 ub = *(const ushort4*)(so + base + 4);
  float v[8];
  v[0] = bf2f(ua.x); v[1] = bf2f(ua.y); v[2] = bf2f(ua.z); v[3] = bf2f(ua.w);
  v[4] = bf2f(ub.x); v[5] = bf2f(ub.y); v[6] = bf2f(ub.z); v[7] = bf2f(ub.w);
  float s = 0.f, sq = 0.f;
#pragma unroll
  for (int j = 0; j < 8; ++j) { s += v[j]; sq += v[j] * v[j]; }
  s = wredsum(s);
  sq = wredsum(sq);
  const int wave = t >> 6, lane = t & 63;
  if (lane == 0) { red[0][wave] = s; red[1][wave] = sq; }
  __syncthreads();
  s = red[0][0] + red[0][1] + red[0][2] + red[0][3];
  sq = red[1][0] + red[1][1] + red[1][2] + red[1][3];
  float mu = s * (1.f / 2048.f);
  float var = sq * (1.f / 2048.f) - mu * mu;
  float rstd = rsqrtf(var + EPS_);
  const int c = h * 64 + d0;
  ushort4 o1, o2;
  float nv;
  nv = (v[0] - mu) * rstd * pnw[c + 0] + pnb[c + 0]; o1.x = to_bf16(nv);
  nv = (v[1] - mu) * rstd * pnw[c + 1] + pnb[c + 1]; o1.y = to_bf16(nv);
  nv = (v[2] - mu) * rstd * pnw[c + 2] + pnb[c + 2]; o1.z = to_bf16(nv);
  nv = (v[3] - mu) * rstd * pnw[c + 3] + pnb[c + 3]; o1.w = to_bf16(nv);
  nv = (v[4] - mu) * rstd * pnw[c + 4] + pnb[c + 4]; o2.x = to_bf16(nv);
  nv = (v[5] - mu) * rstd * pnw[c + 5] + pnb[c + 5]; o2.y = to_bf16(nv);
  nv = (v[6] - mu) * rstd * pnw[c + 6] + pnb[c + 6]; o2.z = to_bf16(nv);
  nv = (v[7] - mu) * rstd * pnw[c + 7] + pnb[c + 7]; o2.w = to_bf16(nv);
  u16* dst = out_bf + (size_t)r * 2048 + c;
  *(ushort4*)dst = o1;
  *(ushort4*)(dst + 4) = o2;
}

extern "C" void kernel_launch(void* const* d_in, const int* in_sizes, int n_in,
                              void* d_out, int out_size, void* d_ws, size_t ws_size,
                              hipStream_t stream) {
  const float* hs = (const float*)d_in[0];
  const float* q_w = (const float*)d_in[1];
  const float* v_w = (const float*)d_in[2];
  const float* o_w = (const float*)d_in[3];
  const float* cqw = (const float*)d_in[4];
  const float* cqb = (const float*)d_in[5];
  const float* ckw = (const float*)d_in[6];
  const float* ckb = (const float*)d_in[7];
  const float* lrw = (const float*)d_in[8];
  const float* lrb = (const float*)d_in[9];
  const float* lti = (const float*)d_in[10];
  const float* tnw = (const float*)d_in[11];
  const float* tnb = (const float*)d_in[12];
  const float* W1in = (const float*)d_in[13];
  const float* b1in = (const float*)d_in[14];
  const float* pnw = (const float*)d_in[15];
  const float* pnb = (const float*)d_in[16];

  char* ws = (char*)d_ws;
  u16* hs_bf  = (u16*)(ws + 0);
  u16* XQs    = (u16*)(ws + 0);
  u16* xq_bf  = (u16*)(ws + 33554432);
  u16* scano  = (u16*)(ws + 33554432);
  u16* XKs    = (u16*)(ws + 67108864);
  u16* normed = (u16*)(ws + 67108864);
  u16* XVs    = (u16*)(ws + 100663296);
  u16* qw_bf  = (u16*)(ws + 134217728);
  u16* ow_bf  = (u16*)(ws + 134217728);
  u16* vw_bf  = (u16*)(ws + 142606336);
  float* slr  = (float*)(ws + 150994944);
  float* outp = (float*)d_out;

  k_cvt<<<16384, 256, 0, stream>>>(hs, hs_bf, 4194304);
  k_cvt<<<4096, 256, 0, stream>>>(q_w, qw_bf, 1048576);
  k_cvt<<<4096, 256, 0, stream>>>(v_w, vw_bf, 1048576);

  dim3 gg(16, 64);
  k_gemm<2><<<gg, 256, 0, stream>>>(hs_bf, qw_bf, xq_bf, 8192, 2048, 2048);
  k_gemm<1><<<gg, 256, 0, stream>>>(hs_bf, vw_bf, XVs, 8192, 2048, 2048);

  k_cvt<<<4096, 256, 0, stream>>>(o_w, ow_bf, 1048576);

  k_slr<<<8192, 256, 0, stream>>>(hs, lrw, lrb, slr);

  k_convrope<<<8192, 256, 0, stream>>>(xq_bf, cqw, cqb, ckw, ckb, XQs, XKs);

  k_scan<<<128, 256, 0, stream>>>(XQs, XKs, XVs, slr, lti, tnw, tnb, W1in, b1in,
                                  scano);

  k_postln<<<8192, 256, 0, stream>>>(scano, pnw, pnb, normed);

  k_gemm<0><<<gg, 256, 0, stream>>>(normed, ow_bf, outp, 8192, 2048, 2048);
}